// Round 15
// baseline (274.486 us; speedup 1.0000x reference)
//
#include <hip/hip_runtime.h>
#include <hip/hip_bf16.h>

#define NQ     14
#define DIM    16384
#define NLAYER 16
#define BATCH  512
#define NT     1024

#define TBL_V2F_STRIDE   528
#define TBL_F_STRIDE     1056
#define TBL_BYTES        (NLAYER * TBL_V2F_STRIDE * 8)

typedef float v2f __attribute__((ext_vector_type(2)));

// bijective LDS swizzle (XOR bits 5..9 into 0..4), BYTE units (float2=8B).
__device__ __forceinline__ constexpr int POSB(int x){ return (x ^ ((x >> 5) & 31)) << 3; }

__device__ __forceinline__ float bf2f(unsigned int u16){
  union { unsigned int i; float f; } v; v.i = u16 << 16; return v.f;
}

__device__ __forceinline__ float thv(const void* th, int i, bool b16){
  return b16 ? bf2f(((const unsigned short*)th)[i]) : ((const float*)th)[i];
}

// Composed CNOT-ring source map (GF(2)-linear)
__device__ int srcF(int x){
  int v = x;
  #pragma unroll
  for (int k = 13; k >= 0; --k){
    int tb = 13 - ((k + 1) % 14);
    v ^= ((v >> (13 - k)) & 1) << tb;
  }
  return v;
}

// complex multiply in 2 VOP3P instructions
__device__ __forceinline__ v2f cmul(v2f a, v2f b){
  v2f t, d;
  asm("v_pk_mul_f32 %0, %1, %2 op_sel:[0,0] op_sel_hi:[1,0]"
      : "=v"(t) : "v"(a), "v"(b));
  asm("v_pk_fma_f32 %0, %1, %2, %3 op_sel:[1,1,0] op_sel_hi:[0,1,1] neg_lo:[0,1,0]"
      : "=v"(d) : "v"(a), "v"(b), "v"(t));
  return d;
}

// RY rotation: FORCED packed (4 x VOP3P). The operator-based v2f version was
// at risk of scalarizing to 8 x f32 ops (r14 VALU accounting showed a 2x gap).
__device__ __forceinline__ void rot2(v2f& a0, v2f& a1, v2f c2, v2f s2){
  v2f m, m2, r0, r1;
  asm("v_pk_mul_f32 %0, %1, %2" : "=v"(m)  : "v"(a0), "v"(c2));
  asm("v_pk_mul_f32 %0, %1, %2" : "=v"(m2) : "v"(a0), "v"(s2));
  asm("v_pk_fma_f32 %0, %1, %2, %3 neg_lo:[1,0,0] neg_hi:[1,0,0]"
      : "=v"(r0) : "v"(a1), "v"(s2), "v"(m));
  asm("v_pk_fma_f32 %0, %1, %2, %3"
      : "=v"(r1) : "v"(a1), "v"(c2), "v"(m2));
  a0 = r0; a1 = r1;
}

// h*cv + p*sv, forced packed (2 x VOP3P)
__device__ __forceinline__ v2f mix2(v2f h, v2f p, v2f cv, v2f sv){
  v2f m, r;
  asm("v_pk_mul_f32 %0, %1, %2" : "=v"(m) : "v"(h), "v"(cv));
  asm("v_pk_fma_f32 %0, %1, %2, %3" : "=v"(r) : "v"(p), "v"(sv), "v"(m));
  return r;
}

template<int CTRL>
__device__ __forceinline__ v2f quad_swap(v2f a){
  union { float f; int i; } xl, xh;
  xl.f = a.x; xh.f = a.y;
  union { int i; float f; } rl, rh;
  rl.i = __builtin_amdgcn_mov_dpp(xl.i, CTRL, 0xf, 0xf, true);
  rh.i = __builtin_amdgcn_mov_dpp(xh.i, CTRL, 0xf, 0xf, true);
  return (v2f){rl.f, rh.f};
}

__device__ __forceinline__ int ph2lt_pos(int idx){
  return (idx & 3) | (((idx >> 6) & 1) << 2) | (((idx >> 2) & 15) << 3);
}

// ---- table precompute kernel: 16 blocks (one per layer) x 512 threads ----
__global__ __launch_bounds__(512)
void qnn_tables(const void* __restrict__ theta, float* __restrict__ ws)
{
  const int t = threadIdx.x, l = blockIdx.x;
  int pred = 0;
  if (t < 336){
    unsigned int w  = ((const unsigned int*)theta)[t];
    unsigned int lo = w & 0xffffu;
    unsigned int e  = (lo >> 7) & 0xffu;
    pred = (e >= 100 && e <= 140) || (lo == 0);
  }
  const bool th_b16 = (__syncthreads_count(pred) > 250);
  const int thb = l * 42;

  {
    int grp = t >> 7, idx = t & 127;
    int tz = thb + ((grp >= 2) ? 28 : 0);
    float ph = 0.f;
    if ((grp & 1) == 0){
      #pragma unroll
      for (int w = 0; w < 7; ++w)
        ph += (((idx >> (6 - w)) & 1) ? 0.5f : -0.5f) * thv(theta, tz + w, th_b16);
    } else {
      #pragma unroll
      for (int w = 7; w < 14; ++w)
        ph += (((idx >> (13 - w)) & 1) ? 0.5f : -0.5f) * thv(theta, tz + w, th_b16);
    }
    float sn, cs; sincosf(ph, &sn, &cs);
    int pos = (grp < 3) ? ((grp << 7) | idx) : (384 | ph2lt_pos(idx));
    ((v2f*)ws)[l * TBL_V2F_STRIDE + pos] = (v2f){cs, sn};
  }
  if (t < 14){
    float sn, cs; sincosf(0.5f * thv(theta, thb + 14 + t, th_b16), &sn, &cs);
    ws[l * TBL_F_STRIDE + 1024 + 2*t]     = cs;
    ws[l * TBL_F_STRIDE + 1024 + 2*t + 1] = sn;
  }
}

// Layer structure (3 barriers + 1 fence; 96 LDS state ops):
//   P1 : gather(CNOT^-1, SGPR tables) + RZ0 + RY q0-3
//   A  : RY q4-7 (reg) + RY q13,q12 (DPP quad_perm)            [fence]
//   B1 : RY q8-11 + RZ2                                         [barrier]
template<int USE_WS>
__global__ __launch_bounds__(NT) __attribute__((amdgpu_waves_per_eu(4, 4)))
void qnn_circuit(const void* __restrict__ zraw,
                 const void* __restrict__ theta,
                 float* __restrict__ out,
                 const float* __restrict__ ws)
{
  __shared__ v2f   S[DIM];
  __shared__ v2f   tbl[512];
  __shared__ float csT[28];
  __shared__ int   sHB[128], sLB[128];
  __shared__ float red[16*5];

  char* Sb = (char*)S;
  const int t = threadIdx.x;
  const int b = blockIdx.x;

  bool th_b16 = false;
  if constexpr (!USE_WS){
    int predt = 0;
    if (t < 336){
      unsigned int w  = ((const unsigned int*)theta)[t];
      unsigned int lo = w & 0xffffu;
      unsigned int e  = (lo >> 7) & 0xffu;
      predt = (e >= 100 && e <= 140) || (lo == 0);
    }
    th_b16 = (__syncthreads_count(predt) > 250);
  }

  int pred = 0;
  if (t < 256){
    unsigned int w  = ((const unsigned int*)zraw)[t];
    unsigned int lo = w & 0xffffu;
    unsigned int e  = (lo >> 7) & 0xffu;
    pred = (e >= 88 && e <= 140) || (lo == 0);
  }
  const bool z_b16 = (__syncthreads_count(pred) > 160);

  if (t < 128){ sHB[t] = POSB(srcF(t << 7)); sLB[t] = POSB(srcF(t)); }

  if (z_b16){
    const uint4* zb = (const uint4*)((const unsigned short*)zraw + (size_t)b * (DIM * 2));
    #pragma unroll 1
    for (int jj = 0; jj < 4; ++jj){
      int x4 = t + NT * jj;
      uint4 w = zb[x4];
      int xb = x4 * 4;
      *(v2f*)(Sb + POSB(xb+0)) = (v2f){bf2f(w.x & 0xffffu), bf2f(w.x >> 16)};
      *(v2f*)(Sb + POSB(xb+1)) = (v2f){bf2f(w.y & 0xffffu), bf2f(w.y >> 16)};
      *(v2f*)(Sb + POSB(xb+2)) = (v2f){bf2f(w.z & 0xffffu), bf2f(w.z >> 16)};
      *(v2f*)(Sb + POSB(xb+3)) = (v2f){bf2f(w.w & 0xffffu), bf2f(w.w >> 16)};
    }
  } else {
    const float4* zf = (const float4*)((const float*)zraw + (size_t)b * DIM);
    #pragma unroll 1
    for (int jj = 0; jj < 4; ++jj){
      int x4 = t + NT * jj;
      float4 w = zf[x4];
      int xb = x4 * 4;
      *(v2f*)(Sb + POSB(xb+0)) = (v2f){w.x, 0.f};
      *(v2f*)(Sb + POSB(xb+1)) = (v2f){w.y, 0.f};
      *(v2f*)(Sb + POSB(xb+2)) = (v2f){w.z, 0.f};
      *(v2f*)(Sb + POSB(xb+3)) = (v2f){w.w, 0.f};
    }
  }
  __syncthreads();

  const int pwb = POSB(t);
  const int hb  = t >> 7;
  const int slB = sLB[t & 127];

  int sH[16];
  #pragma unroll
  for (int j = 0; j < 16; ++j)
    sH[j] = __builtin_amdgcn_readfirstlane(sHB[hb + 8*j]);

  const int wv  = t >> 6, L = t & 63;
  const int pbA  = POSB((wv << 10) | L);
  const int pbB1 = POSB((wv << 10) | ((L >> 2) << 6) | (L & 3));
  const int hB1  = 256 | (wv << 3) | (L >> 3);
  const int lB1  = 384 | (L & 7);
  const float sg0 = (t & 1) ? 1.f : -1.f;
  const float sg1 = (t & 2) ? 1.f : -1.f;

  for (int l = 0; l < NLAYER; ++l){
    // ---- prep: load (or compute) this layer's tables ----
    if constexpr (USE_WS){
      if (t < 512)
        tbl[t] = ((const v2f*)ws)[l * TBL_V2F_STRIDE + t];
      else if (t < 512 + 28)
        csT[t - 512] = ws[l * TBL_F_STRIDE + 1024 + (t - 512)];
    } else {
      const int thb = l * 42;
      if (t < 512){
        int grp = t >> 7, idx = t & 127;
        int tz = thb + ((grp >= 2) ? 28 : 0);
        float ph = 0.f;
        if ((grp & 1) == 0){
          #pragma unroll
          for (int w = 0; w < 7; ++w)
            ph += (((idx >> (6 - w)) & 1) ? 0.5f : -0.5f) * thv(theta, tz + w, th_b16);
        } else {
          #pragma unroll
          for (int w = 7; w < 14; ++w)
            ph += (((idx >> (13 - w)) & 1) ? 0.5f : -0.5f) * thv(theta, tz + w, th_b16);
        }
        float sn, cs; sincosf(ph, &sn, &cs);
        int pos = (grp < 3) ? ((grp << 7) | idx) : (384 | ph2lt_pos(idx));
        tbl[pos] = (v2f){cs, sn};
      } else if (t < 512 + 14){
        int q = t - 512;
        float sn, cs; sincosf(0.5f * thv(theta, thb + 14 + q, th_b16), &sn, &cs);
        csT[2*q] = cs; csT[2*q+1] = sn;
      }
    }

    // ---- P1: gather + RZ0 + RY q0-3 (x = t | (j<<10)) ----
    {
      v2f g[16];
      if (l == 0){
        #pragma unroll
        for (int j = 0; j < 16; ++j) g[j] = *(v2f*)(Sb + (pwb ^ (j << 13)));
      } else {
        #pragma unroll
        for (int j = 0; j < 16; ++j)
          g[j] = *(v2f*)(Sb + (sH[j] ^ slB));
      }
      __syncthreads();

      {
        v2f cl = tbl[128 | (t & 127)];
        #pragma unroll
        for (int j = 0; j < 16; ++j)
          g[j] = cmul(g[j], cmul(tbl[hb + 8*j], cl));
      }
      #pragma unroll
      for (int q = 0; q < 4; ++q){
        v2f c2 = (v2f){csT[2*q],   csT[2*q]};
        v2f s2 = (v2f){csT[2*q+1], csT[2*q+1]};
        int m = 8 >> q;
        #pragma unroll
        for (int j = 0; j < 16; ++j){
          if (j & m) continue;
          rot2(g[j], g[j | m], c2, s2);
        }
      }
      #pragma unroll
      for (int j = 0; j < 16; ++j) *(v2f*)(Sb + (pwb ^ (j << 13))) = g[j];
    }
    __syncthreads();

    // ---- A: RY q4-7 (reg) + q13,q12 (DPP) ----
    {
      v2f h[16];
      #pragma unroll
      for (int j = 0; j < 16; ++j) h[j] = *(v2f*)(Sb + (pbA ^ ((j << 9) | (j << 4))));
      #pragma unroll
      for (int q = 0; q < 4; ++q){
        v2f c2 = (v2f){csT[2*(4+q)],   csT[2*(4+q)]};
        v2f s2 = (v2f){csT[2*(4+q)+1], csT[2*(4+q)+1]};
        int m = 8 >> q;
        #pragma unroll
        for (int j = 0; j < 16; ++j){
          if (j & m) continue;
          rot2(h[j], h[j | m], c2, s2);
        }
      }
      {
        float c13 = csT[26], s13 = csT[27];
        v2f c13v = (v2f){c13, c13};
        v2f s13v = (v2f){sg0 * s13, sg0 * s13};
        #pragma unroll
        for (int j = 0; j < 16; ++j){
          v2f p = quad_swap<0xB1>(h[j]);
          h[j] = mix2(h[j], p, c13v, s13v);
        }
        float c12 = csT[24], s12 = csT[25];
        v2f c12v = (v2f){c12, c12};
        v2f s12v = (v2f){sg1 * s12, sg1 * s12};
        #pragma unroll
        for (int j = 0; j < 16; ++j){
          v2f p = quad_swap<0x4E>(h[j]);
          h[j] = mix2(h[j], p, c12v, s12v);
        }
      }
      #pragma unroll
      for (int j = 0; j < 16; ++j) *(v2f*)(Sb + (pbA ^ ((j << 9) | (j << 4)))) = h[j];
    }
    __threadfence_block();

    // ---- B1: RY q8-11 + RZ2 ----
    {
      v2f h[16];
      #pragma unroll
      for (int j = 0; j < 16; ++j)
        h[j] = *(v2f*)(Sb + (pbB1 ^ ((j << 5) ^ ((j >> 3) << 3))));
      #pragma unroll
      for (int q = 0; q < 4; ++q){
        v2f c2 = (v2f){csT[2*(8+q)],   csT[2*(8+q)]};
        v2f s2 = (v2f){csT[2*(8+q)+1], csT[2*(8+q)+1]};
        int m = 8 >> q;
        #pragma unroll
        for (int j = 0; j < 16; ++j){
          if (j & m) continue;
          rot2(h[j], h[j | m], c2, s2);
        }
      }
      {
        v2f chh = tbl[hB1];
        #pragma unroll
        for (int j = 0; j < 16; ++j)
          h[j] = cmul(h[j], cmul(chh, tbl[lB1 | (j << 3)]));
      }
      #pragma unroll
      for (int j = 0; j < 16; ++j)
        *(v2f*)(Sb + (pbB1 ^ ((j << 5) ^ ((j >> 3) << 3)))) = h[j];
    }
    __syncthreads();
  }

  // ---- measurement ----
  float z0=0.f, z1=0.f, x0s=0.f, x1s=0.f, y0s=0.f;
  {
    v2f g[16];
    #pragma unroll
    for (int j = 0; j < 16; ++j)
      g[j] = *(v2f*)(Sb + (sH[j] ^ slB));

    #pragma unroll
    for (int j = 0; j < 16; ++j){
      float pw = g[j].x*g[j].x + g[j].y*g[j].y;
      z0 += (j & 8) ? -pw : pw;
      z1 += (j & 4) ? -pw : pw;
    }
    #pragma unroll
    for (int j = 0; j < 8; ++j){
      v2f p0 = g[j], p1 = g[j+8];
      x0s += 2.f*(p0.x*p1.x + p0.y*p1.y);
      y0s += 2.f*(p0.x*p1.y - p0.y*p1.x);
    }
    #pragma unroll
    for (int j = 0; j < 16; ++j){
      if (j & 4) continue;
      v2f p0 = g[j], p1 = g[j|4];
      x1s += 2.f*(p0.x*p1.x + p0.y*p1.y);
    }
  }
  #pragma unroll
  for (int o = 32; o >= 1; o >>= 1){
    z0  += __shfl_down(z0,  o, 64);
    z1  += __shfl_down(z1,  o, 64);
    x0s += __shfl_down(x0s, o, 64);
    x1s += __shfl_down(x1s, o, 64);
    y0s += __shfl_down(y0s, o, 64);
  }
  int wid = t >> 6, lane = t & 63;
  if (lane == 0){
    red[wid*5+0]=z0; red[wid*5+1]=z1; red[wid*5+2]=x0s; red[wid*5+3]=x1s; red[wid*5+4]=y0s;
  }
  __syncthreads();
  if (t < 5){
    float sum = 0.f;
    #pragma unroll
    for (int w = 0; w < 16; ++w) sum += red[w*5 + t];
    out[1 + b*5 + t] = sum;
  }
}

__global__ __launch_bounds__(512)
void qnn_loss(const int* __restrict__ y, float* __restrict__ out)
{
  __shared__ float red[8];
  int t = threadIdx.x;
  const float* o = out + 1 + t*5;
  float o0=o[0], o1=o[1], o2=o[2], o3=o[3], o4=o[4];
  float m = fmaxf(fmaxf(fmaxf(o0,o1), fmaxf(o2,o3)), o4);
  float sum = expf(o0-m)+expf(o1-m)+expf(o2-m)+expf(o3-m)+expf(o4-m);
  float lse = m + logf(sum);
  int yi = y[t]; yi = yi < 0 ? 0 : (yi > 4 ? 4 : yi);
  float lb = lse - o[yi];

  #pragma unroll
  for (int ofs = 32; ofs >= 1; ofs >>= 1) lb += __shfl_down(lb, ofs, 64);
  if ((t & 63) == 0) red[t >> 6] = lb;
  __syncthreads();
  if (t == 0){
    float s = 0.f;
    #pragma unroll
    for (int w = 0; w < 8; ++w) s += red[w];
    out[0] = s / (float)BATCH;
  }
}

extern "C" void kernel_launch(void* const* d_in, const int* in_sizes, int n_in,
                              void* d_out, int out_size, void* d_ws, size_t ws_size,
                              hipStream_t stream)
{
  const void* z     = d_in[0];
  const void* theta = d_in[1];
  const int*  y     = (const int*)d_in[2];
  float*      out   = (float*)d_out;
  float*      ws    = (float*)d_ws;

  if (ws_size >= (size_t)TBL_BYTES){
    qnn_tables<<<NLAYER, 512, 0, stream>>>(theta, ws);
    qnn_circuit<1><<<BATCH, NT, 0, stream>>>(z, theta, out, ws);
  } else {
    qnn_circuit<0><<<BATCH, NT, 0, stream>>>(z, theta, out, ws);
  }
  qnn_loss<<<1, 512, 0, stream>>>(y, out);
}

// Round 16
// 248.580 us; speedup vs baseline: 1.1042x; 1.1042x over previous
//
#include <hip/hip_runtime.h>
#include <hip/hip_bf16.h>

#define NQ     14
#define DIM    16384
#define NLAYER 16
#define BATCH  512
#define NT     1024

// precomputed-table layout in d_ws: per layer 528 v2f (512 table + 14 v2f of csT) = 4224 B
#define TBL_V2F_STRIDE   528
#define TBL_F_STRIDE     1056
#define TBL_BYTES        (NLAYER * TBL_V2F_STRIDE * 8)

typedef float v2f __attribute__((ext_vector_type(2)));

// bijective LDS swizzle (XOR bits 5..9 into 0..4), BYTE units (float2=8B).
__device__ __forceinline__ constexpr int POSB(int x){ return (x ^ ((x >> 5) & 31)) << 3; }

__device__ __forceinline__ float bf2f(unsigned int u16){
  union { unsigned int i; float f; } v; v.i = u16 << 16; return v.f;
}

__device__ __forceinline__ float thv(const void* th, int i, bool b16){
  return b16 ? bf2f(((const unsigned short*)th)[i]) : ((const float*)th)[i];
}

// Composed CNOT-ring source map (GF(2)-linear)
__device__ int srcF(int x){
  int v = x;
  #pragma unroll
  for (int k = 13; k >= 0; --k){
    int tb = 13 - ((k + 1) % 14);
    v ^= ((v >> (13 - k)) & 1) << tb;
  }
  return v;
}

// complex multiply in 2 VOP3P instructions
__device__ __forceinline__ v2f cmul(v2f a, v2f b){
  v2f t, d;
  asm("v_pk_mul_f32 %0, %1, %2 op_sel:[0,0] op_sel_hi:[1,0]"
      : "=v"(t) : "v"(a), "v"(b));
  asm("v_pk_fma_f32 %0, %1, %2, %3 op_sel:[1,1,0] op_sel_hi:[0,1,1] neg_lo:[0,1,0]"
      : "=v"(d) : "v"(a), "v"(b), "v"(t));
  return d;
}

// RY rotation: operator form — compiler already emits packed VOP3P and keeps
// scheduling freedom (r15's forced-asm version regressed 249->274 us).
__device__ __forceinline__ void rot2(v2f& a0, v2f& a1, float c, float s){
  v2f c2 = (v2f){c, c}, s2 = (v2f){s, s};
  v2f t0 = a0;
  a0 = a0 * c2 - a1 * s2;
  a1 = t0 * s2 + a1 * c2;
}

template<int CTRL>
__device__ __forceinline__ v2f quad_swap(v2f a){
  union { float f; int i; } xl, xh;
  xl.f = a.x; xh.f = a.y;
  union { int i; float f; } rl, rh;
  rl.i = __builtin_amdgcn_mov_dpp(xl.i, CTRL, 0xf, 0xf, true);
  rh.i = __builtin_amdgcn_mov_dpp(xh.i, CTRL, 0xf, 0xf, true);
  return (v2f){rl.f, rh.f};
}

// scrambled position for the RZ2-low table (B1 broadcast-free layout)
__device__ __forceinline__ int ph2lt_pos(int idx){
  return (idx & 3) | (((idx >> 6) & 1) << 2) | (((idx >> 2) & 15) << 3);
}

// ---- table precompute kernel: 16 blocks (one per layer) x 512 threads ----
__global__ __launch_bounds__(512)
void qnn_tables(const void* __restrict__ theta, float* __restrict__ ws)
{
  const int t = threadIdx.x, l = blockIdx.x;
  int pred = 0;
  if (t < 336){
    unsigned int w  = ((const unsigned int*)theta)[t];
    unsigned int lo = w & 0xffffu;
    unsigned int e  = (lo >> 7) & 0xffu;
    pred = (e >= 100 && e <= 140) || (lo == 0);
  }
  const bool th_b16 = (__syncthreads_count(pred) > 250);
  const int thb = l * 42;

  {
    int grp = t >> 7, idx = t & 127;
    int tz = thb + ((grp >= 2) ? 28 : 0);
    float ph = 0.f;
    if ((grp & 1) == 0){
      #pragma unroll
      for (int w = 0; w < 7; ++w)
        ph += (((idx >> (6 - w)) & 1) ? 0.5f : -0.5f) * thv(theta, tz + w, th_b16);
    } else {
      #pragma unroll
      for (int w = 7; w < 14; ++w)
        ph += (((idx >> (13 - w)) & 1) ? 0.5f : -0.5f) * thv(theta, tz + w, th_b16);
    }
    float sn, cs; sincosf(ph, &sn, &cs);
    int pos = (grp < 3) ? ((grp << 7) | idx) : (384 | ph2lt_pos(idx));
    ((v2f*)ws)[l * TBL_V2F_STRIDE + pos] = (v2f){cs, sn};
  }
  if (t < 14){
    float sn, cs; sincosf(0.5f * thv(theta, thb + 14 + t, th_b16), &sn, &cs);
    ws[l * TBL_F_STRIDE + 1024 + 2*t]     = cs;
    ws[l * TBL_F_STRIDE + 1024 + 2*t + 1] = sn;
  }
}

// Layer structure (3 barriers + 1 fence; 96 LDS state ops):
//   P1 : gather(CNOT^-1, SGPR-hoisted tables) + RZ0 + RY q0-3
//   A  : RY q4-7 (reg) + RY q13,q12 (DPP quad_perm)            [fence]
//   B1 : RY q8-11 + RZ2                                         [barrier]
template<int USE_WS>
__global__ __launch_bounds__(NT) __attribute__((amdgpu_waves_per_eu(4, 4)))
void qnn_circuit(const void* __restrict__ zraw,
                 const void* __restrict__ theta,
                 float* __restrict__ out,
                 const float* __restrict__ ws)
{
  __shared__ v2f   S[DIM];
  __shared__ v2f   tbl[512];            // [0:128)=ph0H [128:256)=ph0L [256:384)=ph2Ht [384:512)=ph2Lt
  __shared__ float csT[28];
  __shared__ int   sHB[128], sLB[128];
  __shared__ float red[16*5];

  char* Sb = (char*)S;
  const int t = threadIdx.x;
  const int b = blockIdx.x;

  bool th_b16 = false;
  if constexpr (!USE_WS){
    int predt = 0;
    if (t < 336){
      unsigned int w  = ((const unsigned int*)theta)[t];
      unsigned int lo = w & 0xffffu;
      unsigned int e  = (lo >> 7) & 0xffu;
      predt = (e >= 100 && e <= 140) || (lo == 0);
    }
    th_b16 = (__syncthreads_count(predt) > 250);
  }

  // ---- sniff z format: bf16 (re,im) pairs vs float32 real-only ----
  int pred = 0;
  if (t < 256){
    unsigned int w  = ((const unsigned int*)zraw)[t];
    unsigned int lo = w & 0xffffu;
    unsigned int e  = (lo >> 7) & 0xffu;
    pred = (e >= 88 && e <= 140) || (lo == 0);
  }
  const bool z_b16 = (__syncthreads_count(pred) > 160);

  if (t < 128){ sHB[t] = POSB(srcF(t << 7)); sLB[t] = POSB(srcF(t)); }

  // ---- load z -> LDS (swizzled) ----
  if (z_b16){
    const uint4* zb = (const uint4*)((const unsigned short*)zraw + (size_t)b * (DIM * 2));
    #pragma unroll 1
    for (int jj = 0; jj < 4; ++jj){
      int x4 = t + NT * jj;
      uint4 w = zb[x4];
      int xb = x4 * 4;
      *(v2f*)(Sb + POSB(xb+0)) = (v2f){bf2f(w.x & 0xffffu), bf2f(w.x >> 16)};
      *(v2f*)(Sb + POSB(xb+1)) = (v2f){bf2f(w.y & 0xffffu), bf2f(w.y >> 16)};
      *(v2f*)(Sb + POSB(xb+2)) = (v2f){bf2f(w.z & 0xffffu), bf2f(w.z >> 16)};
      *(v2f*)(Sb + POSB(xb+3)) = (v2f){bf2f(w.w & 0xffffu), bf2f(w.w >> 16)};
    }
  } else {
    const float4* zf = (const float4*)((const float*)zraw + (size_t)b * DIM);
    #pragma unroll 1
    for (int jj = 0; jj < 4; ++jj){
      int x4 = t + NT * jj;
      float4 w = zf[x4];
      int xb = x4 * 4;
      *(v2f*)(Sb + POSB(xb+0)) = (v2f){w.x, 0.f};
      *(v2f*)(Sb + POSB(xb+1)) = (v2f){w.y, 0.f};
      *(v2f*)(Sb + POSB(xb+2)) = (v2f){w.z, 0.f};
      *(v2f*)(Sb + POSB(xb+3)) = (v2f){w.w, 0.f};
    }
  }
  __syncthreads();

  const int pwb = POSB(t);
  const int hb  = t >> 7;         // wave-uniform
  const int slB = sLB[t & 127];

  // gather table: wave-uniform & loop-invariant -> hoist into SGPRs
  int sH[16];
  #pragma unroll
  for (int j = 0; j < 16; ++j)
    sH[j] = __builtin_amdgcn_readfirstlane(sHB[hb + 8*j]);

  const int wv  = t >> 6, L = t & 63;
  const int pbA  = POSB((wv << 10) | L);
  const int pbB1 = POSB((wv << 10) | ((L >> 2) << 6) | (L & 3));
  const int hB1  = 256 | (wv << 3) | (L >> 3);
  const int lB1  = 384 | (L & 7);
  const float sg0 = (t & 1) ? 1.f : -1.f;
  const float sg1 = (t & 2) ? 1.f : -1.f;

  for (int l = 0; l < NLAYER; ++l){
    // ---- prep: load (or compute) this layer's tables ----
    if constexpr (USE_WS){
      if (t < 512)
        tbl[t] = ((const v2f*)ws)[l * TBL_V2F_STRIDE + t];
      else if (t < 512 + 28)
        csT[t - 512] = ws[l * TBL_F_STRIDE + 1024 + (t - 512)];
    } else {
      const int thb = l * 42;
      if (t < 512){
        int grp = t >> 7, idx = t & 127;
        int tz = thb + ((grp >= 2) ? 28 : 0);
        float ph = 0.f;
        if ((grp & 1) == 0){
          #pragma unroll
          for (int w = 0; w < 7; ++w)
            ph += (((idx >> (6 - w)) & 1) ? 0.5f : -0.5f) * thv(theta, tz + w, th_b16);
        } else {
          #pragma unroll
          for (int w = 7; w < 14; ++w)
            ph += (((idx >> (13 - w)) & 1) ? 0.5f : -0.5f) * thv(theta, tz + w, th_b16);
        }
        float sn, cs; sincosf(ph, &sn, &cs);
        int pos = (grp < 3) ? ((grp << 7) | idx) : (384 | ph2lt_pos(idx));
        tbl[pos] = (v2f){cs, sn};
      } else if (t < 512 + 14){
        int q = t - 512;
        float sn, cs; sincosf(0.5f * thv(theta, thb + 14 + q, th_b16), &sn, &cs);
        csT[2*q] = cs; csT[2*q+1] = sn;
      }
    }

    // ---- P1: gather + RZ0 + RY q0-3 (x = t | (j<<10)) ----
    {
      v2f g[16];
      if (l == 0){
        #pragma unroll
        for (int j = 0; j < 16; ++j) g[j] = *(v2f*)(Sb + (pwb ^ (j << 13)));
      } else {
        #pragma unroll
        for (int j = 0; j < 16; ++j)
          g[j] = *(v2f*)(Sb + (sH[j] ^ slB));
      }
      __syncthreads();   // gathers done; this layer's tables visible

      {
        v2f cl = tbl[128 | (t & 127)];
        #pragma unroll
        for (int j = 0; j < 16; ++j)
          g[j] = cmul(g[j], cmul(tbl[hb + 8*j], cl));
      }
      #pragma unroll
      for (int q = 0; q < 4; ++q){
        float c = csT[2*q], sn = csT[2*q+1];
        int m = 8 >> q;
        #pragma unroll
        for (int j = 0; j < 16; ++j){
          if (j & m) continue;
          rot2(g[j], g[j | m], c, sn);
        }
      }
      #pragma unroll
      for (int j = 0; j < 16; ++j) *(v2f*)(Sb + (pwb ^ (j << 13))) = g[j];
    }
    __syncthreads();

    // ---- A: RY q4-7 (reg) + q13,q12 (DPP) ----
    {
      v2f h[16];
      #pragma unroll
      for (int j = 0; j < 16; ++j) h[j] = *(v2f*)(Sb + (pbA ^ ((j << 9) | (j << 4))));
      #pragma unroll
      for (int q = 0; q < 4; ++q){
        float c = csT[2*(4+q)], sn = csT[2*(4+q)+1];
        int m = 8 >> q;
        #pragma unroll
        for (int j = 0; j < 16; ++j){
          if (j & m) continue;
          rot2(h[j], h[j | m], c, sn);
        }
      }
      {
        float c13 = csT[26], s13 = csT[27];
        v2f c13v = (v2f){c13, c13};
        v2f s13v = (v2f){sg0 * s13, sg0 * s13};
        #pragma unroll
        for (int j = 0; j < 16; ++j){
          v2f p = quad_swap<0xB1>(h[j]);
          h[j] = h[j] * c13v + p * s13v;
        }
        float c12 = csT[24], s12 = csT[25];
        v2f c12v = (v2f){c12, c12};
        v2f s12v = (v2f){sg1 * s12, sg1 * s12};
        #pragma unroll
        for (int j = 0; j < 16; ++j){
          v2f p = quad_swap<0x4E>(h[j]);
          h[j] = h[j] * c12v + p * s12v;
        }
      }
      #pragma unroll
      for (int j = 0; j < 16; ++j) *(v2f*)(Sb + (pbA ^ ((j << 9) | (j << 4)))) = h[j];
    }
    __threadfence_block();

    // ---- B1: RY q8-11 + RZ2 ----
    {
      v2f h[16];
      #pragma unroll
      for (int j = 0; j < 16; ++j)
        h[j] = *(v2f*)(Sb + (pbB1 ^ ((j << 5) ^ ((j >> 3) << 3))));
      #pragma unroll
      for (int q = 0; q < 4; ++q){
        float c = csT[2*(8+q)], sn = csT[2*(8+q)+1];
        int m = 8 >> q;
        #pragma unroll
        for (int j = 0; j < 16; ++j){
          if (j & m) continue;
          rot2(h[j], h[j | m], c, sn);
        }
      }
      {
        v2f chh = tbl[hB1];
        #pragma unroll
        for (int j = 0; j < 16; ++j)
          h[j] = cmul(h[j], cmul(chh, tbl[lB1 | (j << 3)]));
      }
      #pragma unroll
      for (int j = 0; j < 16; ++j)
        *(v2f*)(Sb + (pbB1 ^ ((j << 5) ^ ((j >> 3) << 3)))) = h[j];
    }
    __syncthreads();
  }

  // ---- measurement ----
  float z0=0.f, z1=0.f, x0s=0.f, x1s=0.f, y0s=0.f;
  {
    v2f g[16];
    #pragma unroll
    for (int j = 0; j < 16; ++j)
      g[j] = *(v2f*)(Sb + (sH[j] ^ slB));

    #pragma unroll
    for (int j = 0; j < 16; ++j){
      float pw = g[j].x*g[j].x + g[j].y*g[j].y;
      z0 += (j & 8) ? -pw : pw;
      z1 += (j & 4) ? -pw : pw;
    }
    #pragma unroll
    for (int j = 0; j < 8; ++j){
      v2f p0 = g[j], p1 = g[j+8];
      x0s += 2.f*(p0.x*p1.x + p0.y*p1.y);
      y0s += 2.f*(p0.x*p1.y - p0.y*p1.x);
    }
    #pragma unroll
    for (int j = 0; j < 16; ++j){
      if (j & 4) continue;
      v2f p0 = g[j], p1 = g[j|4];
      x1s += 2.f*(p0.x*p1.x + p0.y*p1.y);
    }
  }
  #pragma unroll
  for (int o = 32; o >= 1; o >>= 1){
    z0  += __shfl_down(z0,  o, 64);
    z1  += __shfl_down(z1,  o, 64);
    x0s += __shfl_down(x0s, o, 64);
    x1s += __shfl_down(x1s, o, 64);
    y0s += __shfl_down(y0s, o, 64);
  }
  int wid = t >> 6, lane = t & 63;
  if (lane == 0){
    red[wid*5+0]=z0; red[wid*5+1]=z1; red[wid*5+2]=x0s; red[wid*5+3]=x1s; red[wid*5+4]=y0s;
  }
  __syncthreads();
  if (t < 5){
    float sum = 0.f;
    #pragma unroll
    for (int w = 0; w < 16; ++w) sum += red[w*5 + t];
    out[1 + b*5 + t] = sum;
  }
}

__global__ __launch_bounds__(512)
void qnn_loss(const int* __restrict__ y, float* __restrict__ out)
{
  __shared__ float red[8];
  int t = threadIdx.x;
  const float* o = out + 1 + t*5;
  float o0=o[0], o1=o[1], o2=o[2], o3=o[3], o4=o[4];
  float m = fmaxf(fmaxf(fmaxf(o0,o1), fmaxf(o2,o3)), o4);
  float sum = expf(o0-m)+expf(o1-m)+expf(o2-m)+expf(o3-m)+expf(o4-m);
  float lse = m + logf(sum);
  int yi = y[t]; yi = yi < 0 ? 0 : (yi > 4 ? 4 : yi);
  float lb = lse - o[yi];

  #pragma unroll
  for (int ofs = 32; ofs >= 1; ofs >>= 1) lb += __shfl_down(lb, ofs, 64);
  if ((t & 63) == 0) red[t >> 6] = lb;
  __syncthreads();
  if (t == 0){
    float s = 0.f;
    #pragma unroll
    for (int w = 0; w < 8; ++w) s += red[w];
    out[0] = s / (float)BATCH;
  }
}

extern "C" void kernel_launch(void* const* d_in, const int* in_sizes, int n_in,
                              void* d_out, int out_size, void* d_ws, size_t ws_size,
                              hipStream_t stream)
{
  const void* z     = d_in[0];
  const void* theta = d_in[1];
  const int*  y     = (const int*)d_in[2];
  float*      out   = (float*)d_out;
  float*      ws    = (float*)d_ws;

  if (ws_size >= (size_t)TBL_BYTES){
    qnn_tables<<<NLAYER, 512, 0, stream>>>(theta, ws);
    qnn_circuit<1><<<BATCH, NT, 0, stream>>>(z, theta, out, ws);
  } else {
    qnn_circuit<0><<<BATCH, NT, 0, stream>>>(z, theta, out, ws);
  }
  qnn_loss<<<1, 512, 0, stream>>>(y, out);
}